// Round 9
// baseline (318.522 us; speedup 1.0000x reference)
//
#include <hip/hip_runtime.h>
#include <hip/hip_fp16.h>

#define IN_F 24
#define HID 64
#define NB 512      // dst buckets (node ranges)
#define NPB 512     // partition blocks (edge slices)
#define GSZ_MAX 256 // max nodes per bucket (ceil(100000/512) = 196)
#define PBUF 7168   // LDS pair capacity per bucket (mean ~6250, +11 sigma)

typedef unsigned int u32;

// bucket of node d:  k = floor(d*NB/n)
// node range of bucket b (exact inverse):  [ceil(b*n/NB), ceil((b+1)*n/NB))
__device__ __forceinline__ int bucket_lo(int b, int n) {
    return (int)(((long long)b * n + NB - 1) / NB);
}

// ---------------- pass 1a: per-(block,bucket) histogram ----------------
__global__ __launch_bounds__(256) void k_pcount(const int* __restrict__ dst,
                                                u32* __restrict__ pc, int e, int n) {
    __shared__ u32 h[NB];
    for (int j = threadIdx.x; j < NB; j += 256) h[j] = 0;
    __syncthreads();
    int blk = blockIdx.x;
    long long begin = (long long)e * blk / NPB;
    long long end   = (long long)e * (blk + 1) / NPB;
    for (long long i = begin + threadIdx.x; i < end; i += 256) {
        int k = (int)((long long)dst[i] * NB / n);
        atomicAdd(&h[k], 1u);
    }
    __syncthreads();
    for (int j = threadIdx.x; j < NB; j += 256) pc[(size_t)blk * NB + j] = h[j];
}

// ---------------- pass 1b: offsets. pc[blk][bkt] -> absolute output base ----------------
__global__ void k_pscan(u32* __restrict__ pc) {
    __shared__ u32 s[NB];
    int t = threadIdx.x;
    u32 run = 0;
    for (int blk = 0; blk < NPB; ++blk) {
        u32 v = pc[(size_t)blk * NB + t];
        pc[(size_t)blk * NB + t] = run;
        run += v;
    }
    s[t] = run;
    __syncthreads();
    for (int off = 1; off < NB; off <<= 1) {
        u32 v2 = (t >= off) ? s[t - off] : 0;
        __syncthreads();
        s[t] += v2;
        __syncthreads();
    }
    u32 base = s[t] - run;  // exclusive bucket base
    for (int blk = 0; blk < NPB; ++blk) pc[(size_t)blk * NB + t] += base;
}

// ---------------- pass 1c: scatter (dst,src) pairs into bucket order ----------------
__global__ __launch_bounds__(256) void k_part(const int* __restrict__ src,
                                              const int* __restrict__ dst,
                                              const u32* __restrict__ pc,
                                              int2* __restrict__ pairs, int e, int n) {
    __shared__ u32 cur[NB];
    int blk = blockIdx.x;
    for (int j = threadIdx.x; j < NB; j += 256) cur[j] = pc[(size_t)blk * NB + j];
    __syncthreads();
    long long begin = (long long)e * blk / NPB;
    long long end   = (long long)e * (blk + 1) / NPB;
    for (long long i = begin + threadIdx.x; i < end; i += 256) {
        int d = dst[i];
        int sv = src[i];
        int k = (int)((long long)d * NB / n);
        u32 pos = atomicAdd(&cur[k], 1u);
        pairs[pos] = make_int2(d, sv);
    }
}

// ---------------- pass 2: per-bucket mini-CSR in LDS ----------------
__global__ __launch_bounds__(256) void k_bucket(const int2* __restrict__ pairs,
                                                const u32* __restrict__ pc,
                                                int* __restrict__ cnt,
                                                int* __restrict__ row_start,
                                                float* __restrict__ dinv,
                                                int* __restrict__ csr_src, int e, int n) {
    __shared__ int2 pbuf[PBUF];
    __shared__ u32 h[GSZ_MAX];
    __shared__ u32 cur[GSZ_MAX];
    __shared__ u32 sc[GSZ_MAX];
    int b = blockIdx.x;
    int lo = bucket_lo(b, n);        // exact inverse of k = d*NB/n
    int hi = bucket_lo(b + 1, n);
    int gsz = hi - lo;               // <= ceil(n/NB) = 196 <= GSZ_MAX
    u32 start = pc[b];
    u32 endp = (b + 1 < NB) ? pc[b + 1] : (u32)e;
    int nbp = (int)(endp - start);
    for (int j = threadIdx.x; j < GSZ_MAX; j += 256) h[j] = 0;
    __syncthreads();
    int stored = nbp < PBUF ? nbp : PBUF;
    for (int i = threadIdx.x; i < stored; i += 256) {
        int2 p = pairs[start + i];
        pbuf[i] = p;
        atomicAdd(&h[p.x - lo], 1u);
    }
    for (int i = PBUF + threadIdx.x; i < nbp; i += 256) {  // overflow path (rare)
        int2 p = pairs[start + i];
        atomicAdd(&h[p.x - lo], 1u);
    }
    __syncthreads();
    // inclusive scan over GSZ_MAX (=256) counters
    int t = threadIdx.x;
    u32 v = h[t];
    sc[t] = v;
    __syncthreads();
    for (int off = 1; off < 256; off <<= 1) {
        u32 v2 = (t >= off) ? sc[t - off] : 0;
        __syncthreads();
        sc[t] += v2;
        __syncthreads();
    }
    u32 excl = sc[t] - v;
    if (t < gsz) {
        cnt[lo + t] = (int)v;
        row_start[lo + t] = (int)(start + excl);
        dinv[lo + t] = rsqrtf((float)(v + 1));  // +1 self-loop
        cur[t] = excl;
    }
    __syncthreads();
    for (int i = threadIdx.x; i < stored; i += 256) {
        int2 p = pbuf[i];
        u32 pos = atomicAdd(&cur[p.x - lo], 1u);
        csr_src[start + pos] = p.y;
    }
    for (int i = PBUF + threadIdx.x; i < nbp; i += 256) {
        int2 p = pairs[start + i];
        u32 pos = atomicAdd(&cur[p.x - lo], 1u);
        csr_src[start + pos] = p.y;
    }
}

// pack pre-scaled source features: xs[i][f] = f16(x[i][f] * dinv[i])
__global__ void k_pack(const float* __restrict__ x, const float* __restrict__ dinv,
                       __half* __restrict__ xs, int n) {
    int t = blockIdx.x * blockDim.x + threadIdx.x;
    int node = t >> 5;
    int f = t & 31;
    if (node >= n || f >= IN_F) return;
    xs[(long long)node * IN_F + f] = __float2half(x[(long long)node * IN_F + f] * dinv[node]);
}

// ---------------- layer 1 aggregation: 16-lane group per node, half2 payload, unroll-8 ----------------
__global__ void k_agg1(const float* __restrict__ x, const __half2* __restrict__ xs2,
                       const float* __restrict__ dinv, const int* __restrict__ row_start,
                       const int* __restrict__ cnt, const int* __restrict__ csr_src,
                       float2* __restrict__ aggX2, int n) {
    int t = blockIdx.x * blockDim.x + threadIdx.x;
    int node = t >> 4;
    int f2 = t & 15;
    if (node >= n || f2 >= 12) return;
    int row = row_start[node];
    int c = cnt[node];
    float ax = 0.0f, ay = 0.0f;
    int j = 0;
    for (; j + 8 <= c; j += 8) {
        const int* cp = csr_src + row + j;
        int s0 = cp[0], s1 = cp[1], s2 = cp[2], s3 = cp[3];
        int s4 = cp[4], s5 = cp[5], s6 = cp[6], s7 = cp[7];
        __half2 h0 = xs2[s0 * 12 + f2];
        __half2 h1 = xs2[s1 * 12 + f2];
        __half2 h2 = xs2[s2 * 12 + f2];
        __half2 h3 = xs2[s3 * 12 + f2];
        __half2 h4 = xs2[s4 * 12 + f2];
        __half2 h5 = xs2[s5 * 12 + f2];
        __half2 h6 = xs2[s6 * 12 + f2];
        __half2 h7 = xs2[s7 * 12 + f2];
        float2 f0 = __half22float2(h0), f1 = __half22float2(h1);
        float2 f2v = __half22float2(h2), f3 = __half22float2(h3);
        float2 f4 = __half22float2(h4), f5 = __half22float2(h5);
        float2 f6 = __half22float2(h6), f7 = __half22float2(h7);
        ax += (f0.x + f1.x) + (f2v.x + f3.x) + ((f4.x + f5.x) + (f6.x + f7.x));
        ay += (f0.y + f1.y) + (f2v.y + f3.y) + ((f4.y + f5.y) + (f6.y + f7.y));
    }
    for (; j < c; ++j) {
        int s = csr_src[row + j];
        float2 fv = __half22float2(xs2[s * 12 + f2]);
        ax += fv.x;
        ay += fv.y;
    }
    float dn = dinv[node];
    float sx = x[(long long)node * IN_F + 2 * f2];
    float sy = x[(long long)node * IN_F + 2 * f2 + 1];
    float2 outv;
    outv.x = (ax + sx * dn) * dn;
    outv.y = (ay + sy * dn) * dn;
    aggX2[(long long)node * 12 + f2] = outv;
}

// ---------------- fused: h1 = relu(aggX@W1+b1); zs = (h1 . W2) * dinv ----------------
__global__ void k_hidden_z(const float* __restrict__ aggX, const float* __restrict__ W1,
                           const float* __restrict__ b1, const float* __restrict__ W2,
                           const float* __restrict__ dinv, float* __restrict__ zs, int n) {
    __shared__ float w[IN_F * HID];
    __shared__ float w2s[HID];
    __shared__ float b1s[HID];
    for (int j = threadIdx.x; j < IN_F * HID; j += blockDim.x) w[j] = W1[j];
    if (threadIdx.x < HID) { w2s[threadIdx.x] = W2[threadIdx.x]; b1s[threadIdx.x] = b1[threadIdx.x]; }
    __syncthreads();
    int t = blockIdx.x * blockDim.x + threadIdx.x;
    int node = t >> 6;
    int f = t & 63;
    if (node >= n) return;
    const float* xr = aggX + (long long)node * IN_F;
    float acc = b1s[f];
#pragma unroll
    for (int k = 0; k < IN_F; ++k) acc += xr[k] * w[k * HID + f];
    float v = fmaxf(acc, 0.0f) * w2s[f];
#pragma unroll
    for (int off = 32; off > 0; off >>= 1) v += __shfl_down(v, off);
    if (f == 0) zs[node] = v * dinv[node];
}

// ---------------- layer 2 gather ----------------
__global__ void k_out(const float* __restrict__ zs, const float* __restrict__ dinv,
                      const int* __restrict__ row_start, const int* __restrict__ cnt,
                      const int* __restrict__ csr_src, const float* __restrict__ b2,
                      float* __restrict__ out, int n) {
    int t = blockIdx.x * blockDim.x + threadIdx.x;
    int node = t >> 6;
    int lane = t & 63;
    if (node >= n) return;
    int row = row_start[node];
    int c = cnt[node];
    float v = 0.0f;
    for (int j = lane; j < c; j += 64) {
        v += zs[csr_src[row + j]];
    }
#pragma unroll
    for (int off = 32; off > 0; off >>= 1) v += __shfl_down(v, off);
    if (lane == 0) {
        out[node] = b2[0] + dinv[node] * (zs[node] + v);
    }
}

extern "C" void kernel_launch(void* const* d_in, const int* in_sizes, int n_in,
                              void* d_out, int out_size, void* d_ws, size_t ws_size,
                              hipStream_t stream) {
    const float* x   = (const float*)d_in[0];
    const int*   ei  = (const int*)d_in[1];
    const float* W1  = (const float*)d_in[2];
    const float* b1  = (const float*)d_in[3];
    const float* W2  = (const float*)d_in[4];
    const float* b2  = (const float*)d_in[5];
    float* out = (float*)d_out;

    const int n = in_sizes[0] / IN_F;      // 100000
    const int e = in_sizes[1] / 2;         // 3200000
    const int* src = ei;
    const int* dst = ei + e;

    const int B = 256;

    // workspace layout. pairs (CSR build) overlays aggX/zs/xs (compute):
    // lifetimes are disjoint (pairs dead after k_bucket; xs/aggX/zs born after).
    char* base = (char*)d_ws;
    int2* pairs    = (int2*)base;                       // e int2 (25.6 MB)
    float* aggX    = (float*)base;                      // n*24 f32 (9.6 MB)   [overlay]
    float* zs      = aggX + (size_t)n * IN_F;           // n f32              [overlay]
    __half* xs     = (__half*)(zs + n);                 // n*24 f16           [overlay]
    char* after    = base + (size_t)e * sizeof(int2);
    int* cnt       = (int*)after;
    int* row_start = cnt + n;
    int* csr_src   = row_start + n;                     // e ints (12.8 MB)
    float* dinv    = (float*)(csr_src + e);
    u32* pc        = (u32*)(dinv + n);                  // NPB*NB u32 (1 MB)

    // CSR build: single-read two-level bucket sort (no device-scope atomics)
    k_pcount<<<NPB, B, 0, stream>>>(dst, pc, e, n);
    k_pscan<<<1, NB, 0, stream>>>(pc);
    k_part<<<NPB, B, 0, stream>>>(src, dst, pc, pairs, e, n);
    k_bucket<<<NB, B, 0, stream>>>(pairs, pc, cnt, row_start, dinv, csr_src, e, n);

    // pack pre-scaled f16 features (needs dinv; overlays dead pairs region)
    const long long n32 = (long long)n * 32;
    k_pack<<<(int)((n32 + B - 1) / B), B, 0, stream>>>(x, dinv, xs, n);

    // layer 1: gather-aggregate xs (16 lanes/node), then fused transform + zs
    const long long n16 = (long long)n * 16;
    k_agg1<<<(int)((n16 + B - 1) / B), B, 0, stream>>>(x, (const __half2*)xs, dinv,
                                                      row_start, cnt, csr_src,
                                                      (float2*)aggX, n);
    const long long n64 = (long long)n * 64;
    k_hidden_z<<<(int)((n64 + B - 1) / B), B, 0, stream>>>(aggX, W1, b1, W2, dinv, zs, n);

    // layer 2: gather zs
    k_out<<<(int)((n64 + B - 1) / B), B, 0, stream>>>(zs, dinv, row_start, cnt, csr_src, b2, out, n);
}

// Round 10
// 275.073 us; speedup vs baseline: 1.1580x; 1.1580x over previous
//
#include <hip/hip_runtime.h>
#include <hip/hip_fp16.h>

#define IN_F 24
#define HID 64
#define NB 512      // dst buckets (node ranges)
#define NPB 512     // partition blocks (edge slices)
#define GSZ_MAX 256 // max nodes per bucket (ceil(100000/512) = 196)
#define PBUF 7168   // LDS pair capacity per bucket (mean ~6250, +11 sigma)

typedef unsigned int u32;

// bucket of node d:  k = floor(d*NB/n)
// node range of bucket b (exact inverse):  [ceil(b*n/NB), ceil((b+1)*n/NB))
__device__ __forceinline__ int bucket_lo(int b, int n) {
    return (int)(((long long)b * n + NB - 1) / NB);
}

// ---------------- pass 1a: per-(block,bucket) histogram ----------------
__global__ __launch_bounds__(256) void k_pcount(const int* __restrict__ dst,
                                                u32* __restrict__ pc, int e, int n) {
    __shared__ u32 h[NB];
    for (int j = threadIdx.x; j < NB; j += 256) h[j] = 0;
    __syncthreads();
    int blk = blockIdx.x;
    long long begin = (long long)e * blk / NPB;
    long long end   = (long long)e * (blk + 1) / NPB;
    for (long long i = begin + threadIdx.x; i < end; i += 256) {
        int k = (int)((long long)dst[i] * NB / n);
        atomicAdd(&h[k], 1u);
    }
    __syncthreads();
    for (int j = threadIdx.x; j < NB; j += 256) pc[(size_t)blk * NB + j] = h[j];
}

// ---------------- pass 1b-parallel: per-column exclusive scan ----------------
// block t: scan pc[0..NPB-1][t] in place (within-column offsets), emit colsum[t].
__global__ __launch_bounds__(256) void k_pscan_a(u32* __restrict__ pc,
                                                 u32* __restrict__ colsum) {
    __shared__ u32 ps[256];
    int t = blockIdx.x;   // column (bucket)
    int tid = threadIdx.x;
    u32 a = pc[(size_t)(2 * tid) * NB + t];
    u32 b = pc[(size_t)(2 * tid + 1) * NB + t];
    ps[tid] = a + b;
    __syncthreads();
    for (int off = 1; off < 256; off <<= 1) {
        u32 v = (tid >= off) ? ps[tid - off] : 0;
        __syncthreads();
        ps[tid] += v;
        __syncthreads();
    }
    u32 excl = ps[tid] - (a + b);
    pc[(size_t)(2 * tid) * NB + t] = excl;
    pc[(size_t)(2 * tid + 1) * NB + t] = excl + a;
    if (tid == 255) colsum[t] = ps[255];
}

// exclusive scan of the 512 column sums -> bucket bases
__global__ void k_pscan_b(const u32* __restrict__ colsum, u32* __restrict__ basep) {
    __shared__ u32 s[NB];
    int t = threadIdx.x;
    u32 v = colsum[t];
    s[t] = v;
    __syncthreads();
    for (int off = 1; off < NB; off <<= 1) {
        u32 v2 = (t >= off) ? s[t - off] : 0;
        __syncthreads();
        s[t] += v2;
        __syncthreads();
    }
    basep[t] = s[t] - v;
}

// ---------------- pass 1c: scatter (dst,src) pairs into bucket order ----------------
__global__ __launch_bounds__(256) void k_part(const int* __restrict__ src,
                                              const int* __restrict__ dst,
                                              const u32* __restrict__ pc,
                                              const u32* __restrict__ basep,
                                              int2* __restrict__ pairs, int e, int n) {
    __shared__ u32 cur[NB];
    int blk = blockIdx.x;
    for (int j = threadIdx.x; j < NB; j += 256)
        cur[j] = pc[(size_t)blk * NB + j] + basep[j];
    __syncthreads();
    long long begin = (long long)e * blk / NPB;
    long long end   = (long long)e * (blk + 1) / NPB;
    for (long long i = begin + threadIdx.x; i < end; i += 256) {
        int d = dst[i];
        int sv = src[i];
        int k = (int)((long long)d * NB / n);
        u32 pos = atomicAdd(&cur[k], 1u);
        pairs[pos] = make_int2(d, sv);
    }
}

// ---------------- pass 2: per-bucket mini-CSR in LDS ----------------
__global__ __launch_bounds__(256) void k_bucket(const int2* __restrict__ pairs,
                                                const u32* __restrict__ basep,
                                                int* __restrict__ cnt,
                                                int* __restrict__ row_start,
                                                float* __restrict__ dinv,
                                                int* __restrict__ csr_src, int e, int n) {
    __shared__ int2 pbuf[PBUF];
    __shared__ u32 h[GSZ_MAX];
    __shared__ u32 cur[GSZ_MAX];
    __shared__ u32 sc[GSZ_MAX];
    int b = blockIdx.x;
    int lo = bucket_lo(b, n);        // exact inverse of k = d*NB/n
    int hi = bucket_lo(b + 1, n);
    int gsz = hi - lo;               // <= ceil(n/NB) = 196 <= GSZ_MAX
    u32 start = basep[b];
    u32 endp = (b + 1 < NB) ? basep[b + 1] : (u32)e;
    int nbp = (int)(endp - start);
    for (int j = threadIdx.x; j < GSZ_MAX; j += 256) h[j] = 0;
    __syncthreads();
    int stored = nbp < PBUF ? nbp : PBUF;
    for (int i = threadIdx.x; i < stored; i += 256) {
        int2 p = pairs[start + i];
        pbuf[i] = p;
        atomicAdd(&h[p.x - lo], 1u);
    }
    for (int i = PBUF + threadIdx.x; i < nbp; i += 256) {  // overflow path (rare)
        int2 p = pairs[start + i];
        atomicAdd(&h[p.x - lo], 1u);
    }
    __syncthreads();
    // inclusive scan over GSZ_MAX (=256) counters
    int t = threadIdx.x;
    u32 v = h[t];
    sc[t] = v;
    __syncthreads();
    for (int off = 1; off < 256; off <<= 1) {
        u32 v2 = (t >= off) ? sc[t - off] : 0;
        __syncthreads();
        sc[t] += v2;
        __syncthreads();
    }
    u32 excl = sc[t] - v;
    if (t < gsz) {
        cnt[lo + t] = (int)v;
        row_start[lo + t] = (int)(start + excl);
        dinv[lo + t] = rsqrtf((float)(v + 1));  // +1 self-loop
        cur[t] = excl;
    }
    __syncthreads();
    for (int i = threadIdx.x; i < stored; i += 256) {
        int2 p = pbuf[i];
        u32 pos = atomicAdd(&cur[p.x - lo], 1u);
        csr_src[start + pos] = p.y;
    }
    for (int i = PBUF + threadIdx.x; i < nbp; i += 256) {
        int2 p = pairs[start + i];
        u32 pos = atomicAdd(&cur[p.x - lo], 1u);
        csr_src[start + pos] = p.y;
    }
}

// pack pre-scaled source features: xs[i][f] = f16(x[i][f] * dinv[i])
__global__ void k_pack(const float* __restrict__ x, const float* __restrict__ dinv,
                       __half* __restrict__ xs, int n) {
    int t = blockIdx.x * blockDim.x + threadIdx.x;
    int node = t >> 5;
    int f = t & 31;
    if (node >= n || f >= IN_F) return;
    xs[(long long)node * IN_F + f] = __float2half(x[(long long)node * IN_F + f] * dinv[node]);
}

// ---------------- layer 1 aggregation: 16-lane group per node, half2 payload, unroll-8 ----------------
__global__ void k_agg1(const float* __restrict__ x, const __half2* __restrict__ xs2,
                       const float* __restrict__ dinv, const int* __restrict__ row_start,
                       const int* __restrict__ cnt, const int* __restrict__ csr_src,
                       float2* __restrict__ aggX2, int n) {
    int t = blockIdx.x * blockDim.x + threadIdx.x;
    int node = t >> 4;
    int f2 = t & 15;
    if (node >= n || f2 >= 12) return;
    int row = row_start[node];
    int c = cnt[node];
    float ax = 0.0f, ay = 0.0f;
    int j = 0;
    for (; j + 8 <= c; j += 8) {
        const int* cp = csr_src + row + j;
        int s0 = cp[0], s1 = cp[1], s2 = cp[2], s3 = cp[3];
        int s4 = cp[4], s5 = cp[5], s6 = cp[6], s7 = cp[7];
        __half2 h0 = xs2[s0 * 12 + f2];
        __half2 h1 = xs2[s1 * 12 + f2];
        __half2 h2 = xs2[s2 * 12 + f2];
        __half2 h3 = xs2[s3 * 12 + f2];
        __half2 h4 = xs2[s4 * 12 + f2];
        __half2 h5 = xs2[s5 * 12 + f2];
        __half2 h6 = xs2[s6 * 12 + f2];
        __half2 h7 = xs2[s7 * 12 + f2];
        float2 f0 = __half22float2(h0), f1 = __half22float2(h1);
        float2 f2v = __half22float2(h2), f3 = __half22float2(h3);
        float2 f4 = __half22float2(h4), f5 = __half22float2(h5);
        float2 f6 = __half22float2(h6), f7 = __half22float2(h7);
        ax += (f0.x + f1.x) + (f2v.x + f3.x) + ((f4.x + f5.x) + (f6.x + f7.x));
        ay += (f0.y + f1.y) + (f2v.y + f3.y) + ((f4.y + f5.y) + (f6.y + f7.y));
    }
    for (; j < c; ++j) {
        int s = csr_src[row + j];
        float2 fv = __half22float2(xs2[s * 12 + f2]);
        ax += fv.x;
        ay += fv.y;
    }
    float dn = dinv[node];
    float sx = x[(long long)node * IN_F + 2 * f2];
    float sy = x[(long long)node * IN_F + 2 * f2 + 1];
    float2 outv;
    outv.x = (ax + sx * dn) * dn;
    outv.y = (ay + sy * dn) * dn;
    aggX2[(long long)node * 12 + f2] = outv;
}

// ---------------- fused: h1 = relu(aggX@W1+b1); zs = (h1 . W2) * dinv ----------------
__global__ void k_hidden_z(const float* __restrict__ aggX, const float* __restrict__ W1,
                           const float* __restrict__ b1, const float* __restrict__ W2,
                           const float* __restrict__ dinv, float* __restrict__ zs, int n) {
    __shared__ float w[IN_F * HID];
    __shared__ float w2s[HID];
    __shared__ float b1s[HID];
    for (int j = threadIdx.x; j < IN_F * HID; j += blockDim.x) w[j] = W1[j];
    if (threadIdx.x < HID) { w2s[threadIdx.x] = W2[threadIdx.x]; b1s[threadIdx.x] = b1[threadIdx.x]; }
    __syncthreads();
    int t = blockIdx.x * blockDim.x + threadIdx.x;
    int node = t >> 6;
    int f = t & 63;
    if (node >= n) return;
    const float* xr = aggX + (long long)node * IN_F;
    float acc = b1s[f];
#pragma unroll
    for (int k = 0; k < IN_F; ++k) acc += xr[k] * w[k * HID + f];
    float v = fmaxf(acc, 0.0f) * w2s[f];
#pragma unroll
    for (int off = 32; off > 0; off >>= 1) v += __shfl_down(v, off);
    if (f == 0) zs[node] = v * dinv[node];
}

// ---------------- layer 2 gather ----------------
__global__ void k_out(const float* __restrict__ zs, const float* __restrict__ dinv,
                      const int* __restrict__ row_start, const int* __restrict__ cnt,
                      const int* __restrict__ csr_src, const float* __restrict__ b2,
                      float* __restrict__ out, int n) {
    int t = blockIdx.x * blockDim.x + threadIdx.x;
    int node = t >> 6;
    int lane = t & 63;
    if (node >= n) return;
    int row = row_start[node];
    int c = cnt[node];
    float v = 0.0f;
    for (int j = lane; j < c; j += 64) {
        v += zs[csr_src[row + j]];
    }
#pragma unroll
    for (int off = 32; off > 0; off >>= 1) v += __shfl_down(v, off);
    if (lane == 0) {
        out[node] = b2[0] + dinv[node] * (zs[node] + v);
    }
}

extern "C" void kernel_launch(void* const* d_in, const int* in_sizes, int n_in,
                              void* d_out, int out_size, void* d_ws, size_t ws_size,
                              hipStream_t stream) {
    const float* x   = (const float*)d_in[0];
    const int*   ei  = (const int*)d_in[1];
    const float* W1  = (const float*)d_in[2];
    const float* b1  = (const float*)d_in[3];
    const float* W2  = (const float*)d_in[4];
    const float* b2  = (const float*)d_in[5];
    float* out = (float*)d_out;

    const int n = in_sizes[0] / IN_F;      // 100000
    const int e = in_sizes[1] / 2;         // 3200000
    const int* src = ei;
    const int* dst = ei + e;

    const int B = 256;

    // workspace layout. pairs (CSR build) overlays aggX/zs/xs (compute):
    // lifetimes are disjoint (pairs dead after k_bucket; xs/aggX/zs born after).
    char* base = (char*)d_ws;
    int2* pairs    = (int2*)base;                       // e int2 (25.6 MB)
    float* aggX    = (float*)base;                      // n*24 f32 (9.6 MB)   [overlay]
    float* zs      = aggX + (size_t)n * IN_F;           // n f32              [overlay]
    __half* xs     = (__half*)(zs + n);                 // n*24 f16           [overlay]
    char* after    = base + (size_t)e * sizeof(int2);
    int* cnt       = (int*)after;
    int* row_start = cnt + n;
    int* csr_src   = row_start + n;                     // e ints (12.8 MB)
    float* dinv    = (float*)(csr_src + e);
    u32* pc        = (u32*)(dinv + n);                  // NPB*NB u32 (1 MB)
    u32* colsum    = pc + (size_t)NPB * NB;             // NB u32
    u32* basep     = colsum + NB;                       // NB u32

    // CSR build: single-read two-level bucket sort (no device-scope atomics)
    k_pcount<<<NPB, B, 0, stream>>>(dst, pc, e, n);
    k_pscan_a<<<NB, B, 0, stream>>>(pc, colsum);
    k_pscan_b<<<1, NB, 0, stream>>>(colsum, basep);
    k_part<<<NPB, B, 0, stream>>>(src, dst, pc, basep, pairs, e, n);
    k_bucket<<<NB, B, 0, stream>>>(pairs, basep, cnt, row_start, dinv, csr_src, e, n);

    // pack pre-scaled f16 features (needs dinv; overlays dead pairs region)
    const long long n32 = (long long)n * 32;
    k_pack<<<(int)((n32 + B - 1) / B), B, 0, stream>>>(x, dinv, xs, n);

    // layer 1: gather-aggregate xs (16 lanes/node), then fused transform + zs
    const long long n16 = (long long)n * 16;
    k_agg1<<<(int)((n16 + B - 1) / B), B, 0, stream>>>(x, (const __half2*)xs, dinv,
                                                      row_start, cnt, csr_src,
                                                      (float2*)aggX, n);
    const long long n64 = (long long)n * 64;
    k_hidden_z<<<(int)((n64 + B - 1) / B), B, 0, stream>>>(aggX, W1, b1, W2, dinv, zs, n);

    // layer 2: gather zs
    k_out<<<(int)((n64 + B - 1) / B), B, 0, stream>>>(zs, dinv, row_start, cnt, csr_src, b2, out, n);
}

// Round 11
// 244.219 us; speedup vs baseline: 1.3042x; 1.1263x over previous
//
#include <hip/hip_runtime.h>
#include <hip/hip_fp16.h>

#define IN_F 24
#define HID 64
#define NB 512      // dst buckets (node ranges)
#define NPB 512     // partition blocks (edge slices)
#define GSZ_MAX 256 // max nodes per bucket (ceil(100000/512) = 196)
#define PBUF 7168   // LDS pair capacity per bucket (mean ~6250, +11 sigma)

typedef unsigned int u32;

// bucket of node d:  k = floor(d*NB/n)
// node range of bucket b (exact inverse):  [ceil(b*n/NB), ceil((b+1)*n/NB))
__device__ __forceinline__ int bucket_lo(int b, int n) {
    return (int)(((long long)b * n + NB - 1) / NB);
}

// ---------------- pass 1a: per-(slice,bucket) histogram ----------------
__global__ __launch_bounds__(256) void k_pcount(const int* __restrict__ dst,
                                                u32* __restrict__ pc, int e, int n) {
    __shared__ u32 h[NB];
    for (int j = threadIdx.x; j < NB; j += 256) h[j] = 0;
    __syncthreads();
    int blk = blockIdx.x;
    long long begin = (long long)e * blk / NPB;
    long long end   = (long long)e * (blk + 1) / NPB;
    for (long long i = begin + threadIdx.x; i < end; i += 256) {
        int k = (int)((long long)dst[i] * NB / n);
        atomicAdd(&h[k], 1u);
    }
    __syncthreads();
    for (int j = threadIdx.x; j < NB; j += 256) pc[(size_t)blk * NB + j] = h[j];
}

// ---------------- pass 1b-parallel: per-column exclusive scan ----------------
__global__ __launch_bounds__(256) void k_pscan_a(u32* __restrict__ pc,
                                                 u32* __restrict__ colsum) {
    __shared__ u32 ps[256];
    int t = blockIdx.x;   // column (bucket)
    int tid = threadIdx.x;
    u32 a = pc[(size_t)(2 * tid) * NB + t];
    u32 b = pc[(size_t)(2 * tid + 1) * NB + t];
    ps[tid] = a + b;
    __syncthreads();
    for (int off = 1; off < 256; off <<= 1) {
        u32 v = (tid >= off) ? ps[tid - off] : 0;
        __syncthreads();
        ps[tid] += v;
        __syncthreads();
    }
    u32 excl = ps[tid] - (a + b);
    pc[(size_t)(2 * tid) * NB + t] = excl;
    pc[(size_t)(2 * tid + 1) * NB + t] = excl + a;
    if (tid == 255) colsum[t] = ps[255];
}

// exclusive scan of the 512 column sums -> bucket bases
__global__ void k_pscan_b(const u32* __restrict__ colsum, u32* __restrict__ basep) {
    __shared__ u32 s[NB];
    int t = threadIdx.x;
    u32 v = colsum[t];
    s[t] = v;
    __syncthreads();
    for (int off = 1; off < NB; off <<= 1) {
        u32 v2 = (t >= off) ? s[t - off] : 0;
        __syncthreads();
        s[t] += v2;
        __syncthreads();
    }
    basep[t] = s[t] - v;
}

// ---------------- pass 1c: scatter (dst,src) pairs into bucket order ----------------
// XCD-affine slice remap: slices 0..63 -> blocks {0,8,16,...} (same XCD by round-robin),
// so adjacent bucket segments coalesce in ONE L2 before write-back (3.2 MB/XCD < 4 MB L2).
__global__ __launch_bounds__(256) void k_part(const int* __restrict__ src,
                                              const int* __restrict__ dst,
                                              const u32* __restrict__ pc,
                                              const u32* __restrict__ basep,
                                              int2* __restrict__ pairs, int e, int n) {
    __shared__ u32 cur[NB];
    int blk = (blockIdx.x & 7) * (NPB / 8) + (blockIdx.x >> 3);
    for (int j = threadIdx.x; j < NB; j += 256)
        cur[j] = pc[(size_t)blk * NB + j] + basep[j];
    __syncthreads();
    long long begin = (long long)e * blk / NPB;
    long long end   = (long long)e * (blk + 1) / NPB;
    for (long long i = begin + threadIdx.x; i < end; i += 256) {
        int d = dst[i];
        int sv = src[i];
        int k = (int)((long long)d * NB / n);
        u32 pos = atomicAdd(&cur[k], 1u);
        pairs[pos] = make_int2(d, sv);
    }
}

// ---------------- pass 2: per-bucket mini-CSR in LDS ----------------
__global__ __launch_bounds__(256) void k_bucket(const int2* __restrict__ pairs,
                                                const u32* __restrict__ basep,
                                                int* __restrict__ cnt,
                                                int* __restrict__ row_start,
                                                float* __restrict__ dinv,
                                                int* __restrict__ csr_src, int e, int n) {
    __shared__ int2 pbuf[PBUF];
    __shared__ u32 h[GSZ_MAX];
    __shared__ u32 cur[GSZ_MAX];
    __shared__ u32 sc[GSZ_MAX];
    int b = blockIdx.x;
    int lo = bucket_lo(b, n);
    int hi = bucket_lo(b + 1, n);
    int gsz = hi - lo;               // <= GSZ_MAX
    u32 start = basep[b];
    u32 endp = (b + 1 < NB) ? basep[b + 1] : (u32)e;
    int nbp = (int)(endp - start);
    for (int j = threadIdx.x; j < GSZ_MAX; j += 256) h[j] = 0;
    __syncthreads();
    int stored = nbp < PBUF ? nbp : PBUF;
    for (int i = threadIdx.x; i < stored; i += 256) {
        int2 p = pairs[start + i];
        pbuf[i] = p;
        atomicAdd(&h[p.x - lo], 1u);
    }
    for (int i = PBUF + threadIdx.x; i < nbp; i += 256) {  // overflow path (rare)
        int2 p = pairs[start + i];
        atomicAdd(&h[p.x - lo], 1u);
    }
    __syncthreads();
    int t = threadIdx.x;
    u32 v = h[t];
    sc[t] = v;
    __syncthreads();
    for (int off = 1; off < 256; off <<= 1) {
        u32 v2 = (t >= off) ? sc[t - off] : 0;
        __syncthreads();
        sc[t] += v2;
        __syncthreads();
    }
    u32 excl = sc[t] - v;
    if (t < gsz) {
        cnt[lo + t] = (int)v;
        row_start[lo + t] = (int)(start + excl);
        dinv[lo + t] = rsqrtf((float)(v + 1));  // +1 self-loop
        cur[t] = excl;
    }
    __syncthreads();
    for (int i = threadIdx.x; i < stored; i += 256) {
        int2 p = pbuf[i];
        u32 pos = atomicAdd(&cur[p.x - lo], 1u);
        csr_src[start + pos] = p.y;
    }
    for (int i = PBUF + threadIdx.x; i < nbp; i += 256) {
        int2 p = pairs[start + i];
        u32 pos = atomicAdd(&cur[p.x - lo], 1u);
        csr_src[start + pos] = p.y;
    }
}

// pack pre-scaled source features: xs[i][f] = f16(x[i][f] * dinv[i])
__global__ void k_pack(const float* __restrict__ x, const float* __restrict__ dinv,
                       __half* __restrict__ xs, int n) {
    int t = blockIdx.x * blockDim.x + threadIdx.x;
    int node = t >> 5;
    int f = t & 31;
    if (node >= n || f >= IN_F) return;
    xs[(long long)node * IN_F + f] = __float2half(x[(long long)node * IN_F + f] * dinv[node]);
}

// ---------------- layer 1 aggregation: 16-lane group per node, half2 payload, unroll-8 ----------------
__global__ void k_agg1(const float* __restrict__ x, const __half2* __restrict__ xs2,
                       const float* __restrict__ dinv, const int* __restrict__ row_start,
                       const int* __restrict__ cnt, const int* __restrict__ csr_src,
                       float2* __restrict__ aggX2, int n) {
    int t = blockIdx.x * blockDim.x + threadIdx.x;
    int node = t >> 4;
    int f2 = t & 15;
    if (node >= n || f2 >= 12) return;
    int row = row_start[node];
    int c = cnt[node];
    float ax = 0.0f, ay = 0.0f;
    int j = 0;
    for (; j + 8 <= c; j += 8) {
        const int* cp = csr_src + row + j;
        int s0 = cp[0], s1 = cp[1], s2 = cp[2], s3 = cp[3];
        int s4 = cp[4], s5 = cp[5], s6 = cp[6], s7 = cp[7];
        __half2 h0 = xs2[s0 * 12 + f2];
        __half2 h1 = xs2[s1 * 12 + f2];
        __half2 h2 = xs2[s2 * 12 + f2];
        __half2 h3 = xs2[s3 * 12 + f2];
        __half2 h4 = xs2[s4 * 12 + f2];
        __half2 h5 = xs2[s5 * 12 + f2];
        __half2 h6 = xs2[s6 * 12 + f2];
        __half2 h7 = xs2[s7 * 12 + f2];
        float2 f0 = __half22float2(h0), f1 = __half22float2(h1);
        float2 f2v = __half22float2(h2), f3 = __half22float2(h3);
        float2 f4 = __half22float2(h4), f5 = __half22float2(h5);
        float2 f6 = __half22float2(h6), f7 = __half22float2(h7);
        ax += (f0.x + f1.x) + (f2v.x + f3.x) + ((f4.x + f5.x) + (f6.x + f7.x));
        ay += (f0.y + f1.y) + (f2v.y + f3.y) + ((f4.y + f5.y) + (f6.y + f7.y));
    }
    for (; j < c; ++j) {
        int s = csr_src[row + j];
        float2 fv = __half22float2(xs2[s * 12 + f2]);
        ax += fv.x;
        ay += fv.y;
    }
    float dn = dinv[node];
    float sx = x[(long long)node * IN_F + 2 * f2];
    float sy = x[(long long)node * IN_F + 2 * f2 + 1];
    float2 outv;
    outv.x = (ax + sx * dn) * dn;
    outv.y = (ay + sy * dn) * dn;
    aggX2[(long long)node * 12 + f2] = outv;
}

// ---------------- fused layer-1 transform + layer-2 lin: one thread per node ----------------
// h[f] in VGPRs; W1 read at wave-uniform LDS addresses (broadcast); no cross-lane reduction.
__global__ __launch_bounds__(256) void k_hidden_z(const float* __restrict__ aggX,
                                                  const float* __restrict__ W1,
                                                  const float* __restrict__ b1,
                                                  const float* __restrict__ W2,
                                                  const float* __restrict__ dinv,
                                                  float* __restrict__ zs, int n) {
    __shared__ float w[IN_F * HID];   // k-major: w[k*64+f]
    __shared__ float w2s[HID];
    __shared__ float b1s[HID];
    for (int j = threadIdx.x; j < IN_F * HID; j += 256) w[j] = W1[j];
    if (threadIdx.x < HID) { w2s[threadIdx.x] = W2[threadIdx.x]; b1s[threadIdx.x] = b1[threadIdx.x]; }
    __syncthreads();
    int node = blockIdx.x * 256 + threadIdx.x;
    if (node >= n) return;
    float h[HID];
#pragma unroll
    for (int f = 0; f < HID; ++f) h[f] = b1s[f];
    const float4* xp = (const float4*)(aggX + (long long)node * IN_F);  // 96 B row, 16B-aligned
#pragma unroll
    for (int kk = 0; kk < IN_F / 4; ++kk) {
        float4 xv = xp[kk];
        const float* w0 = w + (kk * 4) * HID;
#pragma unroll
        for (int f = 0; f < HID; ++f) h[f] += xv.x * w0[f];
        const float* w1r = w0 + HID;
#pragma unroll
        for (int f = 0; f < HID; ++f) h[f] += xv.y * w1r[f];
        const float* w2r = w1r + HID;
#pragma unroll
        for (int f = 0; f < HID; ++f) h[f] += xv.z * w2r[f];
        const float* w3r = w2r + HID;
#pragma unroll
        for (int f = 0; f < HID; ++f) h[f] += xv.w * w3r[f];
    }
    float acc = 0.0f;
#pragma unroll
    for (int f = 0; f < HID; ++f) acc += fmaxf(h[f], 0.0f) * w2s[f];
    zs[node] = acc * dinv[node];
}

// ---------------- layer 2 gather ----------------
__global__ void k_out(const float* __restrict__ zs, const float* __restrict__ dinv,
                      const int* __restrict__ row_start, const int* __restrict__ cnt,
                      const int* __restrict__ csr_src, const float* __restrict__ b2,
                      float* __restrict__ out, int n) {
    int t = blockIdx.x * blockDim.x + threadIdx.x;
    int node = t >> 6;
    int lane = t & 63;
    if (node >= n) return;
    int row = row_start[node];
    int c = cnt[node];
    float v = 0.0f;
    for (int j = lane; j < c; j += 64) {
        v += zs[csr_src[row + j]];
    }
#pragma unroll
    for (int off = 32; off > 0; off >>= 1) v += __shfl_down(v, off);
    if (lane == 0) {
        out[node] = b2[0] + dinv[node] * (zs[node] + v);
    }
}

extern "C" void kernel_launch(void* const* d_in, const int* in_sizes, int n_in,
                              void* d_out, int out_size, void* d_ws, size_t ws_size,
                              hipStream_t stream) {
    const float* x   = (const float*)d_in[0];
    const int*   ei  = (const int*)d_in[1];
    const float* W1  = (const float*)d_in[2];
    const float* b1  = (const float*)d_in[3];
    const float* W2  = (const float*)d_in[4];
    const float* b2  = (const float*)d_in[5];
    float* out = (float*)d_out;

    const int n = in_sizes[0] / IN_F;      // 100000
    const int e = in_sizes[1] / 2;         // 3200000
    const int* src = ei;
    const int* dst = ei + e;

    const int B = 256;

    // workspace layout. pairs (CSR build) overlays aggX/zs/xs (compute):
    // lifetimes are disjoint (pairs dead after k_bucket; xs/aggX/zs born after).
    char* base = (char*)d_ws;
    int2* pairs    = (int2*)base;                       // e int2 (25.6 MB)
    float* aggX    = (float*)base;                      // n*24 f32 (9.6 MB)   [overlay]
    float* zs      = aggX + (size_t)n * IN_F;           // n f32              [overlay]
    __half* xs     = (__half*)(zs + n);                 // n*24 f16           [overlay]
    char* after    = base + (size_t)e * sizeof(int2);
    int* cnt       = (int*)after;
    int* row_start = cnt + n;
    int* csr_src   = row_start + n;                     // e ints (12.8 MB)
    float* dinv    = (float*)(csr_src + e);
    u32* pc        = (u32*)(dinv + n);                  // NPB*NB u32 (1 MB)
    u32* colsum    = pc + (size_t)NPB * NB;             // NB u32
    u32* basep     = colsum + NB;                       // NB u32

    // CSR build: single-read two-level bucket sort (no device-scope atomics)
    k_pcount<<<NPB, B, 0, stream>>>(dst, pc, e, n);
    k_pscan_a<<<NB, B, 0, stream>>>(pc, colsum);
    k_pscan_b<<<1, NB, 0, stream>>>(colsum, basep);
    k_part<<<NPB, B, 0, stream>>>(src, dst, pc, basep, pairs, e, n);
    k_bucket<<<NB, B, 0, stream>>>(pairs, basep, cnt, row_start, dinv, csr_src, e, n);

    // pack pre-scaled f16 features (needs dinv; overlays dead pairs region)
    const long long n32 = (long long)n * 32;
    k_pack<<<(int)((n32 + B - 1) / B), B, 0, stream>>>(x, dinv, xs, n);

    // layer 1: gather-aggregate xs (16 lanes/node), then fused transform + zs
    const long long n16 = (long long)n * 16;
    k_agg1<<<(int)((n16 + B - 1) / B), B, 0, stream>>>(x, (const __half2*)xs, dinv,
                                                      row_start, cnt, csr_src,
                                                      (float2*)aggX, n);
    k_hidden_z<<<(n + B - 1) / B, B, 0, stream>>>(aggX, W1, b1, W2, dinv, zs, n);

    // layer 2: gather zs
    const long long n64 = (long long)n * 64;
    k_out<<<(int)((n64 + B - 1) / B), B, 0, stream>>>(zs, dinv, row_start, cnt, csr_src, b2, out, n);
}

// Round 12
// 240.477 us; speedup vs baseline: 1.3245x; 1.0156x over previous
//
#include <hip/hip_runtime.h>
#include <hip/hip_fp16.h>

#define IN_F 24
#define HID 64
#define NB 512      // dst buckets (node ranges)
#define NPB 256     // partition blocks (edge slices)
#define GSZ_MAX 256 // max nodes per bucket (ceil(100000/512) = 196)
#define PBUF 7168   // pair capacity per bucket in LDS (mean ~6250, +11 sigma)
#define SRC_BITS 17 // src < 100000 < 2^17; loc < 196 < 2^8

typedef unsigned int u32;

// bucket of node d:  k = floor(d*NB/n)
// node range of bucket b (exact inverse):  [ceil(b*n/NB), ceil((b+1)*n/NB))
__device__ __forceinline__ int bucket_lo(int b, int n) {
    return (int)(((long long)b * n + NB - 1) / NB);
}

// ---------------- pass 1a: per-(slice,bucket) histogram ----------------
__global__ __launch_bounds__(256) void k_pcount(const int* __restrict__ dst,
                                                u32* __restrict__ pc, int e, int n) {
    __shared__ u32 h[NB];
    for (int j = threadIdx.x; j < NB; j += 256) h[j] = 0;
    __syncthreads();
    int blk = blockIdx.x;
    long long begin = (long long)e * blk / NPB;
    long long end   = (long long)e * (blk + 1) / NPB;
    for (long long i = begin + threadIdx.x; i < end; i += 256) {
        int k = (int)((long long)dst[i] * NB / n);
        atomicAdd(&h[k], 1u);
    }
    __syncthreads();
    for (int j = threadIdx.x; j < NB; j += 256) pc[(size_t)blk * NB + j] = h[j];
}

// ---------------- pass 1b-parallel: per-column exclusive scan (NPB=256 rows) ----------------
__global__ __launch_bounds__(256) void k_pscan_a(u32* __restrict__ pc,
                                                 u32* __restrict__ colsum) {
    __shared__ u32 ps[256];
    int t = blockIdx.x;   // column (bucket)
    int tid = threadIdx.x;
    u32 v = pc[(size_t)tid * NB + t];
    ps[tid] = v;
    __syncthreads();
    for (int off = 1; off < 256; off <<= 1) {
        u32 v2 = (tid >= off) ? ps[tid - off] : 0;
        __syncthreads();
        ps[tid] += v2;
        __syncthreads();
    }
    pc[(size_t)tid * NB + t] = ps[tid] - v;   // exclusive within-column
    if (tid == 255) colsum[t] = ps[255];
}

// exclusive scan of the 512 column sums -> bucket bases
__global__ void k_pscan_b(const u32* __restrict__ colsum, u32* __restrict__ basep) {
    __shared__ u32 s[NB];
    int t = threadIdx.x;
    u32 v = colsum[t];
    s[t] = v;
    __syncthreads();
    for (int off = 1; off < NB; off <<= 1) {
        u32 v2 = (t >= off) ? s[t - off] : 0;
        __syncthreads();
        s[t] += v2;
        __syncthreads();
    }
    basep[t] = s[t] - v;
}

// ---------------- pass 1c: scatter packed (loc<<17|src) into bucket order ----------------
__global__ __launch_bounds__(256) void k_part(const int* __restrict__ src,
                                              const int* __restrict__ dst,
                                              const u32* __restrict__ pc,
                                              const u32* __restrict__ basep,
                                              u32* __restrict__ pairs, int e, int n) {
    __shared__ u32 cur[NB];
    int blk = (blockIdx.x & 7) * (NPB / 8) + (blockIdx.x >> 3);  // XCD-affine (perf heuristic)
    for (int j = threadIdx.x; j < NB; j += 256)
        cur[j] = pc[(size_t)blk * NB + j] + basep[j];
    __syncthreads();
    long long begin = (long long)e * blk / NPB;
    long long end   = (long long)e * (blk + 1) / NPB;
    for (long long i = begin + threadIdx.x; i < end; i += 256) {
        int d = dst[i];
        int sv = src[i];
        int k = (int)((long long)d * NB / n);
        u32 loc = (u32)(d - bucket_lo(k, n));
        u32 pos = atomicAdd(&cur[k], 1u);
        pairs[pos] = (loc << SRC_BITS) | (u32)sv;
    }
}

// ---------------- pass 2: per-bucket mini-CSR in LDS ----------------
__global__ __launch_bounds__(256) void k_bucket(const u32* __restrict__ pairs,
                                                const u32* __restrict__ basep,
                                                int* __restrict__ cnt,
                                                int* __restrict__ row_start,
                                                float* __restrict__ dinv,
                                                int* __restrict__ csr_src, int e, int n) {
    __shared__ u32 pbuf[PBUF];
    __shared__ u32 h[GSZ_MAX];
    __shared__ u32 cur[GSZ_MAX];
    __shared__ u32 sc[GSZ_MAX];
    int b = blockIdx.x;
    int lo = bucket_lo(b, n);
    int hi = bucket_lo(b + 1, n);
    int gsz = hi - lo;               // <= GSZ_MAX
    u32 start = basep[b];
    u32 endp = (b + 1 < NB) ? basep[b + 1] : (u32)e;
    int nbp = (int)(endp - start);
    for (int j = threadIdx.x; j < GSZ_MAX; j += 256) h[j] = 0;
    __syncthreads();
    int stored = nbp < PBUF ? nbp : PBUF;
    for (int i = threadIdx.x; i < stored; i += 256) {
        u32 p = pairs[start + i];
        pbuf[i] = p;
        atomicAdd(&h[p >> SRC_BITS], 1u);
    }
    for (int i = PBUF + threadIdx.x; i < nbp; i += 256) {  // overflow path (rare)
        atomicAdd(&h[pairs[start + i] >> SRC_BITS], 1u);
    }
    __syncthreads();
    int t = threadIdx.x;
    u32 v = h[t];
    sc[t] = v;
    __syncthreads();
    for (int off = 1; off < 256; off <<= 1) {
        u32 v2 = (t >= off) ? sc[t - off] : 0;
        __syncthreads();
        sc[t] += v2;
        __syncthreads();
    }
    u32 excl = sc[t] - v;
    if (t < gsz) {
        cnt[lo + t] = (int)v;
        row_start[lo + t] = (int)(start + excl);
        dinv[lo + t] = rsqrtf((float)(v + 1));  // +1 self-loop
        cur[t] = excl;
    }
    __syncthreads();
    for (int i = threadIdx.x; i < stored; i += 256) {
        u32 p = pbuf[i];
        u32 pos = atomicAdd(&cur[p >> SRC_BITS], 1u);
        csr_src[start + pos] = (int)(p & ((1u << SRC_BITS) - 1));
    }
    for (int i = PBUF + threadIdx.x; i < nbp; i += 256) {
        u32 p = pairs[start + i];
        u32 pos = atomicAdd(&cur[p >> SRC_BITS], 1u);
        csr_src[start + pos] = (int)(p & ((1u << SRC_BITS) - 1));
    }
}

// pack pre-scaled source features: xs[i][f] = f16(x[i][f] * dinv[i])
__global__ void k_pack(const float* __restrict__ x, const float* __restrict__ dinv,
                       __half* __restrict__ xs, int n) {
    int t = blockIdx.x * blockDim.x + threadIdx.x;
    int node = t >> 5;
    int f = t & 31;
    if (node >= n || f >= IN_F) return;
    xs[(long long)node * IN_F + f] = __float2half(x[(long long)node * IN_F + f] * dinv[node]);
}

// ---------------- layer 1 aggregation: 16-lane group per node, half2 payload, unroll-8 ----------------
__global__ void k_agg1(const float* __restrict__ x, const __half2* __restrict__ xs2,
                       const float* __restrict__ dinv, const int* __restrict__ row_start,
                       const int* __restrict__ cnt, const int* __restrict__ csr_src,
                       float2* __restrict__ aggX2, int n) {
    int t = blockIdx.x * blockDim.x + threadIdx.x;
    int node = t >> 4;
    int f2 = t & 15;
    if (node >= n || f2 >= 12) return;
    int row = row_start[node];
    int c = cnt[node];
    float ax = 0.0f, ay = 0.0f;
    int j = 0;
    for (; j + 8 <= c; j += 8) {
        const int* cp = csr_src + row + j;
        int s0 = cp[0], s1 = cp[1], s2 = cp[2], s3 = cp[3];
        int s4 = cp[4], s5 = cp[5], s6 = cp[6], s7 = cp[7];
        __half2 h0 = xs2[s0 * 12 + f2];
        __half2 h1 = xs2[s1 * 12 + f2];
        __half2 h2 = xs2[s2 * 12 + f2];
        __half2 h3 = xs2[s3 * 12 + f2];
        __half2 h4 = xs2[s4 * 12 + f2];
        __half2 h5 = xs2[s5 * 12 + f2];
        __half2 h6 = xs2[s6 * 12 + f2];
        __half2 h7 = xs2[s7 * 12 + f2];
        float2 f0 = __half22float2(h0), f1 = __half22float2(h1);
        float2 f2v = __half22float2(h2), f3 = __half22float2(h3);
        float2 f4 = __half22float2(h4), f5 = __half22float2(h5);
        float2 f6 = __half22float2(h6), f7 = __half22float2(h7);
        ax += (f0.x + f1.x) + (f2v.x + f3.x) + ((f4.x + f5.x) + (f6.x + f7.x));
        ay += (f0.y + f1.y) + (f2v.y + f3.y) + ((f4.y + f5.y) + (f6.y + f7.y));
    }
    for (; j < c; ++j) {
        int s = csr_src[row + j];
        float2 fv = __half22float2(xs2[s * 12 + f2]);
        ax += fv.x;
        ay += fv.y;
    }
    float dn = dinv[node];
    float sx = x[(long long)node * IN_F + 2 * f2];
    float sy = x[(long long)node * IN_F + 2 * f2 + 1];
    float2 outv;
    outv.x = (ax + sx * dn) * dn;
    outv.y = (ay + sy * dn) * dn;
    aggX2[(long long)node * 12 + f2] = outv;
}

// ---------------- fused layer-1 transform + layer-2 lin: one thread per node ----------------
__global__ __launch_bounds__(256) void k_hidden_z(const float* __restrict__ aggX,
                                                  const float* __restrict__ W1,
                                                  const float* __restrict__ b1,
                                                  const float* __restrict__ W2,
                                                  const float* __restrict__ dinv,
                                                  float* __restrict__ zs, int n) {
    __shared__ float w[IN_F * HID];   // k-major: w[k*64+f]
    __shared__ float w2s[HID];
    __shared__ float b1s[HID];
    for (int j = threadIdx.x; j < IN_F * HID; j += 256) w[j] = W1[j];
    if (threadIdx.x < HID) { w2s[threadIdx.x] = W2[threadIdx.x]; b1s[threadIdx.x] = b1[threadIdx.x]; }
    __syncthreads();
    int node = blockIdx.x * 256 + threadIdx.x;
    if (node >= n) return;
    float h[HID];
#pragma unroll
    for (int f = 0; f < HID; ++f) h[f] = b1s[f];
    const float4* xp = (const float4*)(aggX + (long long)node * IN_F);
#pragma unroll
    for (int kk = 0; kk < IN_F / 4; ++kk) {
        float4 xv = xp[kk];
        const float* w0 = w + (kk * 4) * HID;
#pragma unroll
        for (int f = 0; f < HID; ++f) h[f] += xv.x * w0[f];
        const float* w1r = w0 + HID;
#pragma unroll
        for (int f = 0; f < HID; ++f) h[f] += xv.y * w1r[f];
        const float* w2r = w1r + HID;
#pragma unroll
        for (int f = 0; f < HID; ++f) h[f] += xv.z * w2r[f];
        const float* w3r = w2r + HID;
#pragma unroll
        for (int f = 0; f < HID; ++f) h[f] += xv.w * w3r[f];
    }
    float acc = 0.0f;
#pragma unroll
    for (int f = 0; f < HID; ++f) acc += fmaxf(h[f], 0.0f) * w2s[f];
    zs[node] = acc * dinv[node];
}

// ---------------- layer 2 gather ----------------
__global__ void k_out(const float* __restrict__ zs, const float* __restrict__ dinv,
                      const int* __restrict__ row_start, const int* __restrict__ cnt,
                      const int* __restrict__ csr_src, const float* __restrict__ b2,
                      float* __restrict__ out, int n) {
    int t = blockIdx.x * blockDim.x + threadIdx.x;
    int node = t >> 6;
    int lane = t & 63;
    if (node >= n) return;
    int row = row_start[node];
    int c = cnt[node];
    float v = 0.0f;
    for (int j = lane; j < c; j += 64) {
        v += zs[csr_src[row + j]];
    }
#pragma unroll
    for (int off = 32; off > 0; off >>= 1) v += __shfl_down(v, off);
    if (lane == 0) {
        out[node] = b2[0] + dinv[node] * (zs[node] + v);
    }
}

extern "C" void kernel_launch(void* const* d_in, const int* in_sizes, int n_in,
                              void* d_out, int out_size, void* d_ws, size_t ws_size,
                              hipStream_t stream) {
    const float* x   = (const float*)d_in[0];
    const int*   ei  = (const int*)d_in[1];
    const float* W1  = (const float*)d_in[2];
    const float* b1  = (const float*)d_in[3];
    const float* W2  = (const float*)d_in[4];
    const float* b2  = (const float*)d_in[5];
    float* out = (float*)d_out;

    const int n = in_sizes[0] / IN_F;      // 100000
    const int e = in_sizes[1] / 2;         // 3200000
    const int* src = ei;
    const int* dst = ei + e;

    const int B = 256;

    // workspace layout. pairs (u32, CSR build) overlays aggX/zs/xs (compute):
    // lifetimes disjoint. Overlay region sized max(4e, 148n) bytes.
    char* base = (char*)d_ws;
    u32* pairs     = (u32*)base;                        // e u32 (12.8 MB)
    float* aggX    = (float*)base;                      // n*24 f32 (9.6 MB)   [overlay]
    float* zs      = aggX + (size_t)n * IN_F;           // n f32              [overlay]
    __half* xs     = (__half*)(zs + n);                 // n*24 f16           [overlay]
    size_t ov = (size_t)e * 4;
    size_t ov2 = (size_t)n * 148;
    if (ov2 > ov) ov = ov2;
    ov = (ov + 255) & ~(size_t)255;
    char* after    = base + ov;
    int* cnt       = (int*)after;
    int* row_start = cnt + n;
    int* csr_src   = row_start + n;                     // e ints (12.8 MB)
    float* dinv    = (float*)(csr_src + e);
    u32* pc        = (u32*)(dinv + n);                  // NPB*NB u32 (0.5 MB)
    u32* colsum    = pc + (size_t)NPB * NB;             // NB u32
    u32* basep     = colsum + NB;                       // NB u32

    // CSR build: single-read two-level bucket sort (no device-scope atomics)
    k_pcount<<<NPB, B, 0, stream>>>(dst, pc, e, n);
    k_pscan_a<<<NB, B, 0, stream>>>(pc, colsum);
    k_pscan_b<<<1, NB, 0, stream>>>(colsum, basep);
    k_part<<<NPB, B, 0, stream>>>(src, dst, pc, basep, pairs, e, n);
    k_bucket<<<NB, B, 0, stream>>>(pairs, basep, cnt, row_start, dinv, csr_src, e, n);

    // pack pre-scaled f16 features (needs dinv; overlays dead pairs region)
    const long long n32 = (long long)n * 32;
    k_pack<<<(int)((n32 + B - 1) / B), B, 0, stream>>>(x, dinv, xs, n);

    // layer 1: gather-aggregate xs (16 lanes/node), then fused transform + zs
    const long long n16 = (long long)n * 16;
    k_agg1<<<(int)((n16 + B - 1) / B), B, 0, stream>>>(x, (const __half2*)xs, dinv,
                                                      row_start, cnt, csr_src,
                                                      (float2*)aggX, n);
    k_hidden_z<<<(n + B - 1) / B, B, 0, stream>>>(aggX, W1, b1, W2, dinv, zs, n);

    // layer 2: gather zs
    const long long n64 = (long long)n * 64;
    k_out<<<(int)((n64 + B - 1) / B), B, 0, stream>>>(zs, dinv, row_start, cnt, csr_src, b2, out, n);
}